// Round 6
// baseline (231.713 us; speedup 1.0000x reference)
//
#include <hip/hip_runtime.h>

#define IMG_H 512
#define IMG_W 512
#define RH 16                        // output rows per wave-task
#define STRIPS (IMG_H / RH)          // 32
#define QWAVES 4                     // 4 column-quarters (128 cols each) per row
#define PLANE_N (IMG_H * IMG_W)

typedef float v2f __attribute__((ext_vector_type(2)));

// Gaussian(sigma=1.5, k=3): weights (W_E, W_C, W_E) = W_C * (r, 1, r),
// r = exp(-2/9). Using r-weighted convs M,Q gives mu = k*M, e = k*Q with
// k = W_C^2; the k^3 factor cancels between SSIM num and den, leaving
// adjusted constants c1 = C1/k^2, c2 = C2/k. (2% abs threshold >> fp drift.)
constexpr float RW  = 0.80073744f;     // exp(-2/9)
constexpr float KK  = 0.14776133f;     // W_C^2
constexpr float C1N = 4.58013e-3f;     // 1e-4 / KK^2
constexpr float C2N = 6.09091e-3f;     // 9e-4 / KK

// Raw pixel row: 2 cols of each image + the (lane0/lane63 only) edge pixel.
struct Raw { v2f a, b; float aE, bE; };                     // 6 VGPRs

__device__ __forceinline__ void load_row(const float* __restrict__ A,
                                         const float* __restrict__ B,
                                         int row, int col0, int ecol, Raw& r) {
    if ((unsigned)row < (unsigned)IMG_H) {          // wave-uniform
        const size_t off = (size_t)row * IMG_W;
        r.a = *(const v2f*)(A + off + col0);
        r.b = *(const v2f*)(B + off + col0);
        float ae = 0.f, be = 0.f;
        if (ecol >= 0) {                            // <=2 active lanes
            ae = A[off + ecol];
            be = B[off + ecol];
        }
        r.aE = ae; r.bE = be;
    } else {                                        // rows -1 / 512+ are zero pad
        r.a = (v2f){0.f, 0.f};
        r.b = (v2f){0.f, 0.f};
        r.aE = 0.f; r.bE = 0.f;
    }
}

struct HV { v2f h1, h2, h11, h22, h12; };           // transient, per stanza

// Horizontal r-weighted 3-tap of {a,b,a2,b2,ab}; halo via intra-wave shuffle.
__device__ __forceinline__ void compute_h(const Raw& r, bool lane0, bool lane63,
                                          HV& H) {
    const float ax = r.a.x, ay = r.a.y, bx = r.b.x, by = r.b.y;
    float aL = __shfl_up(ay, 1);
    float bL = __shfl_up(by, 1);
    float aR = __shfl_down(ax, 1);
    float bR = __shfl_down(bx, 1);
    if (lane0)  { aL = r.aE; bL = r.bE; }
    if (lane63) { aR = r.aE; bR = r.bE; }
    const float aL2 = aL*aL, ax2 = ax*ax, ay2 = ay*ay, aR2 = aR*aR;
    const float bL2 = bL*bL, bx2 = bx*bx, by2 = by*by, bR2 = bR*bR;
    const float abL = aL*bL, abx = ax*bx, aby = ay*by, abR = aR*bR;
    H.h1  = (v2f){fmaf(RW, aL  + ay,  ax),  fmaf(RW, ax  + aR,  ay)};
    H.h2  = (v2f){fmaf(RW, bL  + by,  bx),  fmaf(RW, bx  + bR,  by)};
    H.h11 = (v2f){fmaf(RW, aL2 + ay2, ax2), fmaf(RW, ax2 + aR2, ay2)};
    H.h22 = (v2f){fmaf(RW, bL2 + by2, bx2), fmaf(RW, bx2 + bR2, by2)};
    H.h12 = (v2f){fmaf(RW, abL + aby, abx), fmaf(RW, abx + abR, aby)};
}

// Wave-task = (plane, 16-row strip, 128-col quarter). 4 independent waves per
// block; no LDS / barriers / atomics. Vertical conv via 2 running accumulators
// per channel (20 regs vs 30 for a 3-row window) frees room for a 3-slot raw
// rolling buffer => loads issued 2 stanzas (~460 cyc) before use.
__global__ __launch_bounds__(256)
void ssim_main_kernel(const float* __restrict__ img1,
                      const float* __restrict__ img2,
                      float* __restrict__ wsum)
{
    const int t = threadIdx.x;
    const int lane = t & 63;
    const int task = blockIdx.x * 4 + (t >> 6);     // 0..12287
    const int quar  = task & (QWAVES - 1);
    const int strip = (task >> 2) & (STRIPS - 1);
    const int plane = task >> 7;                    // 96 planes
    const int y0 = strip * RH;
    const int col0 = quar * 128 + (lane << 1);
    const bool lane0 = (lane == 0), lane63 = (lane == 63);
    const float* __restrict__ A = img1 + (size_t)plane * PLANE_N;
    const float* __restrict__ B = img2 + (size_t)plane * PLANE_N;

    // edge column: lane0 needs col0-1, lane63 needs col0+2; -1 = none/border
    int ecol = -1;
    if (lane0  && col0 > 0) ecol = col0 - 1;
    if (lane63 && col0 + 2 < IMG_W) ecol = col0 + 2;

    const v2f RWv = {RW, RW};
    const v2f TWO = {2.f, 2.f};
    const v2f MKK = {-KK, -KK};
    const v2f C1v = {C1N, C1N};
    const v2f C2v = {C2N, C2N};

    // Vertical accumulators: entering the stanza that computes h_k,
    // ac0 = r*h_{k-2} + h_{k-1}, ac1 = r*h_{k-1}.
    v2f ac0_1 = {0,0}, ac1_1 = {0,0}, ac0_2 = {0,0}, ac1_2 = {0,0};
    v2f ac0_11 = {0,0}, ac1_11 = {0,0}, ac0_22 = {0,0}, ac1_22 = {0,0};
    v2f ac0_12 = {0,0}, ac1_12 = {0,0};
    v2f vsum = {0.f, 0.f};

    Raw R0, R1, R2;
    // prologue: rows y0-1 -> R0, y0 -> R1 (stanza k consumes R[k%3],
    // loads row y0+1+k into R[(k+2)%3] -- issued 2 stanzas ahead)
    load_row(A, B, y0 - 1, col0, ecol, R0);
    load_row(A, B, y0,     col0, ecol, R1);

#define VF(a, b, c) __builtin_elementwise_fma((a), (b), (c))
#define STANZA(RU, RL, k, DOOUT, DOLOAD)                                    \
    do {                                                                    \
        if (DOLOAD) load_row(A, B, y0 + 1 + (k), col0, ecol, RL);           \
        HV H;                                                               \
        compute_h((RU), lane0, lane63, H);                                  \
        if (DOOUT) {                                                        \
            const v2f M1  = VF(RWv, H.h1,  ac0_1);                          \
            const v2f M2  = VF(RWv, H.h2,  ac0_2);                          \
            const v2f E11 = VF(RWv, H.h11, ac0_11);                         \
            const v2f E22 = VF(RWv, H.h22, ac0_22);                         \
            const v2f E12 = VF(RWv, H.h12, ac0_12);                         \
            const v2f m12 = M1 * M2;                                        \
            const v2f p   = VF(M2, M2, M1 * M1);                            \
            const v2f num1 = VF(TWO, m12, C1v);                             \
            const v2f s12  = VF(MKK, m12, E12);                             \
            const v2f num2 = VF(TWO, s12, C2v);                             \
            const v2f den1 = p + C1v;                                       \
            const v2f tt   = E11 + E22;                                     \
            const v2f sp   = VF(MKK, p, tt);                                \
            const v2f den2 = sp + C2v;                                      \
            const v2f num  = num1 * num2;                                   \
            const v2f den  = den1 * den2;                                   \
            const v2f rv = {__builtin_amdgcn_rcpf(den.x),                   \
                            __builtin_amdgcn_rcpf(den.y)};                  \
            vsum = VF(num, rv, vsum);                                       \
        }                                                                   \
        ac0_1  = ac1_1  + H.h1;   ac1_1  = RWv * H.h1;                      \
        ac0_2  = ac1_2  + H.h2;   ac1_2  = RWv * H.h2;                      \
        ac0_11 = ac1_11 + H.h11;  ac1_11 = RWv * H.h11;                     \
        ac0_22 = ac1_22 + H.h22;  ac1_22 = RWv * H.h22;                     \
        ac0_12 = ac1_12 + H.h12;  ac1_12 = RWv * H.h12;                     \
        __builtin_amdgcn_sched_barrier(0);                                  \
    } while (0)

    STANZA(R0, R2, 0, false, true);                 // h(y0-1)
    STANZA(R1, R0, 1, false, true);                 // h(y0)
    STANZA(R2, R1, 2, true,  true);                 // h(y0+1) -> out y0
#pragma unroll
    for (int g = 1; g <= 4; ++g) {                  // k = 3g, 3g+1, 3g+2
        const int k = 3 * g;
        STANZA(R0, R2, k,     true, true);
        STANZA(R1, R0, k + 1, true, true);
        STANZA(R2, R1, k + 2, true, true);
    }
    STANZA(R0, R2, 15, true, true);                 // loads row y0+16 (last)
    STANZA(R1, R0, 16, true, false);
    STANZA(R2, R1, 17, true, false);
#undef STANZA
#undef VF

    float tsum = vsum.x + vsum.y;
#pragma unroll
    for (int off = 32; off; off >>= 1) tsum += __shfl_xor(tsum, off, 64);
    if (lane0) wsum[task] = tsum;   // every slot written every launch
}

// Single block reduces the 12288 per-wave partials (all in L2 by launch time).
__global__ __launch_bounds__(256) void ssim_fin_kernel(
    const float* __restrict__ wsum, float* __restrict__ out, int n)
{
    const int t = threadIdx.x;
    double s = 0.0;
    for (int i = t; i < n; i += 256) s += (double)wsum[i];
#pragma unroll
    for (int off = 32; off; off >>= 1) s += __shfl_xor(s, off, 64);
    __shared__ double wp[4];
    if ((t & 63) == 0) wp[t >> 6] = s;
    __syncthreads();
    if (t == 0) out[0] = 1.0f - (float)(wp[0] + wp[1] + wp[2] + wp[3]);
}

extern "C" void kernel_launch(void* const* d_in, const int* in_sizes, int n_in,
                              void* d_out, int out_size, void* d_ws, size_t ws_size,
                              hipStream_t stream) {
    const float* img1 = (const float*)d_in[0];
    const float* img2 = (const float*)d_in[1];
    float* out = (float*)d_out;
    float* wsum = (float*)d_ws;

    const int planes = in_sizes[0] / PLANE_N;       // 32*3 = 96
    const int tasks = planes * STRIPS * QWAVES;     // 12288 waves
    const int blocks = tasks / 4;                   // 3072

    ssim_main_kernel<<<blocks, 256, 0, stream>>>(img1, img2, wsum);
    ssim_fin_kernel<<<1, 256, 0, stream>>>(wsum, out, tasks);
}